// Round 5
// baseline (514.026 us; speedup 1.0000x reference)
//
#include <hip/hip_runtime.h>
#include <hip/hip_bf16.h>

// Problem constants
#define S_LEN  1024
#define DMODEL 1024
#define NHEADS 16
#define DK     64
#define SCALE  0.125f
// rel table: 257 rows; qrelG pitch 272; rvT pitch 288 (K-pad for 9x32 MFMA).
// Attention is split: far tiles (|r-l|>=128+tile) fold rel_v edge rows into
// V (VT0/VT1 precomputed in gemm_qkv epilogue, fp32-exact); band tiles
// (17 per q-tile) keep the LDS histogram w_s and do w @ rel_v.

typedef __bf16 bf16x8_t __attribute__((ext_vector_type(8)));
typedef __bf16 bf16x4_t __attribute__((ext_vector_type(4)));
typedef float  f32x4_t  __attribute__((ext_vector_type(4)));

#define MFMA16(A, B, C) __builtin_amdgcn_mfma_f32_16x16x32_bf16((A), (B), (C), 0, 0, 0)

__device__ __forceinline__ void async16(const void* g, void* l) {
    __builtin_amdgcn_global_load_lds(
        (const __attribute__((address_space(1))) unsigned int*)g,
        (__attribute__((address_space(3))) unsigned int*)l, 16, 0, 0);
}

// ---------------------------------------------------------------------------
// Kernel 1: cast inputs to bf16 + build padded rel tables.
__global__ __launch_bounds__(256) void cast_all_kernel(
    const float* __restrict__ q, const float* __restrict__ k, const float* __restrict__ v,
    const float* __restrict__ wq, const float* __restrict__ wk,
    const float* __restrict__ wv, const float* __restrict__ wo,
    const float* __restrict__ relk, const float* __restrict__ relv,
    __bf16* __restrict__ Xbf, __bf16* __restrict__ Wall,
    __bf16* __restrict__ relkp, __bf16* __restrict__ rvT,
    __bf16* __restrict__ Wqlo)
{
    const long i = (long)blockIdx.x * 256 + threadIdx.x;   // vec4 index
    if (i < 3145728) {                       // X region
        const int z   = (int)(i >> 20);
        const long rem = i & 1048575;
        const float4 s = ((const float4*)(z == 0 ? q : (z == 1 ? k : v)))[rem];
        bf16x4_t h;
        h[0] = (__bf16)s.x; h[1] = (__bf16)s.y; h[2] = (__bf16)s.z; h[3] = (__bf16)s.w;
        *(bf16x4_t*)(Xbf + ((size_t)z << 22) + rem * 4) = h;
    } else if (i < 3145728 + 1048576) {      // W region
        const long wi = i - 3145728;
        const int z   = (int)(wi >> 18);
        const long rem = wi & 262143;
        const float* src = (z == 0) ? wq : (z == 1) ? wk : (z == 2) ? wv : wo;
        const float4 s = ((const float4*)src)[rem];
        const float xs[4] = {s.x, s.y, s.z, s.w};
        bf16x4_t h;
        #pragma unroll
        for (int t = 0; t < 4; ++t) h[t] = (__bf16)xs[t];
        *(bf16x4_t*)(Wall + ((size_t)z << 20) + rem * 4) = h;
        if (z == 0) {
            bf16x4_t l;
            #pragma unroll
            for (int t = 0; t < 4; ++t) l[t] = (__bf16)(xs[t] - (float)h[t]);
            *(bf16x4_t*)(Wqlo + rem * 4) = l;
        }
    } else if (i < 3145728 + 1048576 + 4352) {   // relk hi+lo (272 rows x 64)
        const long ri = i - (3145728 + 1048576);
        const int j  = (int)(ri >> 4);
        const int d4 = (int)(ri & 15) * 4;
        bf16x4_t h, l;
        if (j < 257) {
            const float4 s = *(const float4*)(relk + j * 64 + d4);
            const float xs[4] = {s.x, s.y, s.z, s.w};
            #pragma unroll
            for (int t = 0; t < 4; ++t) {
                h[t] = (__bf16)xs[t];
                l[t] = (__bf16)(xs[t] - (float)h[t]);
            }
        } else {
            #pragma unroll
            for (int t = 0; t < 4; ++t) { h[t] = (__bf16)0.f; l[t] = (__bf16)0.f; }
        }
        *(bf16x4_t*)(relkp + j * 64 + d4) = h;
        *(bf16x4_t*)(relkp + 17408 + j * 64 + d4) = l;
    } else if (i < 3145728 + 1048576 + 4352 + 4608) { // rvT: [64][288], rvT[d][j]=rel_v[j][d]
        const long ri = i - (3145728 + 1048576 + 4352);
        const int d  = (int)(ri / 72);
        const int j4 = (int)(ri % 72) * 4;
        bf16x4_t o;
        #pragma unroll
        for (int t = 0; t < 4; ++t) {
            const int j = j4 + t;
            o[t] = (j < 257) ? (__bf16)relv[j * 64 + d] : (__bf16)0.f;
        }
        *(bf16x4_t*)(rvT + d * 288 + j4) = o;
    }
}

// ---------------------------------------------------------------------------
// Shared 128x128 tile GEMM core: acc += A(128xK) @ W(128xK)^T, K=1024, BK=32.
__device__ __forceinline__ void gemm128_core(
    const __bf16* __restrict__ A, const __bf16* __restrict__ W,
    __bf16* As, __bf16* Ws, f32x4_t acc[4][4])
{
    const int tid  = threadIdx.x;
    const int lane = tid & 63;
    const int quad = lane >> 4;
    const int l15  = lane & 15;
    const int wid  = tid >> 6;
    const int wm = wid >> 1, wn = wid & 1;

    for (int kt = 0; kt < 32; ++kt) {
        #pragma unroll
        for (int r = 0; r < 2; ++r) {
            const int c = r * 256 + tid;        // 512 chunks of 16B per tile
            const int row = c >> 2, kb = c & 3;
            async16(A + row * 1024 + kt * 32 + kb * 8, As + c * 8);
            async16(W + row * 1024 + kt * 32 + kb * 8, Ws + c * 8);
        }
        __syncthreads();                        // drains vmcnt for global_load_lds
        bf16x8_t af[4], wf[4];
        #pragma unroll
        for (int i = 0; i < 4; ++i) {
            af[i] = *(const bf16x8_t*)(As + (wm * 64 + i * 16 + l15) * 32 + quad * 8);
            wf[i] = *(const bf16x8_t*)(Ws + (wn * 64 + i * 16 + l15) * 32 + quad * 8);
        }
        #pragma unroll
        for (int i = 0; i < 4; ++i)
            #pragma unroll
            for (int j = 0; j < 4; ++j)
                acc[i][j] = MFMA16(af[i], wf[j], acc[i][j]);
        __syncthreads();
    }
}

// ---------------------------------------------------------------------------
// Kernel 2: QKV projections. z=0:Q (W hi+lo for precision), z=1:K [bh][s][d];
// z=2:V transposed [bh][d][s], written in 3 variants: plain, +rel_v[0],
// +rel_v[256] (fp32-exact adds; consumed by the far attention kernel).
__global__ __launch_bounds__(256) void gemm_qkv_kernel(
    const __bf16* __restrict__ Xbf, const __bf16* __restrict__ Wall,
    const __bf16* __restrict__ Wqlo,
    const float* __restrict__ bq, const float* __restrict__ bk, const float* __restrict__ bv,
    const float* __restrict__ relv,
    __bf16* __restrict__ QKVh, __bf16* __restrict__ VT0, __bf16* __restrict__ VT1)
{
    __shared__ __bf16 As[4096], Ws[4096];
    const int z = blockIdx.z;
    const __bf16* A = Xbf + (size_t)z * 4194304 + (size_t)blockIdx.y * 131072;
    const __bf16* W = Wall + (size_t)z * 1048576 + (size_t)blockIdx.x * 131072;
    f32x4_t acc[4][4];
    #pragma unroll
    for (int i = 0; i < 4; ++i)
        #pragma unroll
        for (int j = 0; j < 4; ++j)
            acc[i][j] = (f32x4_t){0.f, 0.f, 0.f, 0.f};

    gemm128_core(A, W, As, Ws, acc);
    if (z == 0)   // Q = Xhi*(Whi+Wlo)
        gemm128_core(A, Wqlo + (size_t)blockIdx.x * 131072, As, Ws, acc);

    const int tid = threadIdx.x, lane = tid & 63, quad = lane >> 4, l15 = lane & 15;
    const int wid = tid >> 6, wm = wid >> 1, wn = wid & 1;
    const int m0 = blockIdx.y * 128 + wm * 64;
    const int n0 = blockIdx.x * 128 + wn * 64;
    const float* bias = (z == 0) ? bq : ((z == 1) ? bk : bv);
    __bf16* dst = QKVh + (size_t)z * 4194304;

    if (z < 2) {
        #pragma unroll
        for (int j = 0; j < 4; ++j) {
            const int n = n0 + j * 16 + l15;
            const float bn = bias[n];
            #pragma unroll
            for (int i = 0; i < 4; ++i) {
                #pragma unroll
                for (int v = 0; v < 4; ++v) {
                    const int m = m0 + i * 16 + quad * 4 + v;
                    dst[((((m >> 10) * 16 + (n >> 6)) << 16)) + ((m & 1023) << 6) + (n & 63)]
                        = (__bf16)(acc[i][j][v] + bn);
                }
            }
        }
    } else {
        #pragma unroll
        for (int j = 0; j < 4; ++j) {
            const int n = n0 + j * 16 + l15;
            const float bn = bias[n];
            const float rv0 = relv[n & 63];            // rel_v[0][d]
            const float rv1 = relv[256 * 64 + (n & 63)]; // rel_v[256][d]
            #pragma unroll
            for (int i = 0; i < 4; ++i) {
                const int m = m0 + i * 16 + quad * 4;
                bf16x4_t pk, p0, p1;
                #pragma unroll
                for (int v = 0; v < 4; ++v) {
                    const float a = acc[i][j][v] + bn;
                    pk[v] = (__bf16)a;
                    p0[v] = (__bf16)(a + rv0);
                    p1[v] = (__bf16)(a + rv1);
                }
                const size_t idx = (((size_t)((m >> 10) * 16 + (n >> 6))) << 16)
                                 + ((n & 63) << 10) + (m & 1023);
                *(bf16x4_t*)(dst + idx) = pk;
                *(bf16x4_t*)(VT0 + idx) = p0;
                *(bf16x4_t*)(VT1 + idx) = p1;
            }
        }
    }
}

// ---------------------------------------------------------------------------
// Kernel 5: output projection, fp32 epilogue straight to d_out.
__global__ __launch_bounds__(256) void gemm_out_kernel(
    const __bf16* __restrict__ ctx, const __bf16* __restrict__ Wo,
    const float* __restrict__ bo, float* __restrict__ out)
{
    __shared__ __bf16 As[4096], Ws[4096];
    const __bf16* A = ctx + (size_t)blockIdx.y * 131072;
    const __bf16* W = Wo + (size_t)blockIdx.x * 131072;
    f32x4_t acc[4][4];
    #pragma unroll
    for (int i = 0; i < 4; ++i)
        #pragma unroll
        for (int j = 0; j < 4; ++j)
            acc[i][j] = (f32x4_t){0.f, 0.f, 0.f, 0.f};
    gemm128_core(A, W, As, Ws, acc);

    const int tid = threadIdx.x, lane = tid & 63, quad = lane >> 4, l15 = lane & 15;
    const int wid = tid >> 6, wm = wid >> 1, wn = wid & 1;
    const int m0 = blockIdx.y * 128 + wm * 64;
    const int n0 = blockIdx.x * 128 + wn * 64;
    #pragma unroll
    for (int j = 0; j < 4; ++j) {
        const int n = n0 + j * 16 + l15;
        const float bn = bo[n];
        #pragma unroll
        for (int i = 0; i < 4; ++i)
            #pragma unroll
            for (int v = 0; v < 4; ++v) {
                const int m = m0 + i * 16 + quad * 4 + v;
                out[(size_t)m * 1024 + n] = acc[i][j][v] + bn;
            }
    }
}

// ---------------------------------------------------------------------------
// Kernel 3a: qrel GEMM. qrelG[bh][l][j] = Q[bh,l]·rel_k[j] (hi+lo), fp16 out.
__global__ __launch_bounds__(256) void qrel_kernel(
    const __bf16* __restrict__ Qh, const __bf16* __restrict__ relkp,
    _Float16* __restrict__ qrelG)
{
    const int tid = threadIdx.x, lane = tid & 63, wid = tid >> 6;
    const int quad = lane >> 4, l15 = lane & 15;
    const int bh = blockIdx.y;
    const int l0 = blockIdx.x * 64 + wid * 16;
    const __bf16* Qbase = Qh + (size_t)bh * 65536;
    const __bf16* relk_hi = relkp;
    const __bf16* relk_lo = relkp + 17408;
    const bf16x8_t aq0 = *(const bf16x8_t*)(Qbase + (l0 + l15) * 64 + quad * 8);
    const bf16x8_t aq1 = *(const bf16x8_t*)(Qbase + (l0 + l15) * 64 + 32 + quad * 8);
    _Float16* out = qrelG + ((size_t)bh * 1024 + l0) * 272;
    for (int nt = 0; nt < 17; ++nt) {
        const int j = nt * 16 + l15;
        const bf16x8_t h0  = *(const bf16x8_t*)(relk_hi + j * 64 + quad * 8);
        const bf16x8_t h1  = *(const bf16x8_t*)(relk_hi + j * 64 + 32 + quad * 8);
        const bf16x8_t lo0 = *(const bf16x8_t*)(relk_lo + j * 64 + quad * 8);
        const bf16x8_t lo1 = *(const bf16x8_t*)(relk_lo + j * 64 + 32 + quad * 8);
        f32x4_t c = (f32x4_t){0.f, 0.f, 0.f, 0.f};
        c = MFMA16(aq0, lo0, c);
        c = MFMA16(aq1, lo1, c);
        c = MFMA16(aq0, h0, c);
        c = MFMA16(aq1, h1, c);
        #pragma unroll
        for (int v = 0; v < 4; ++v)
            out[(quad * 4 + v) * 272 + j] = (_Float16)c[v];
    }
}

// ---------------------------------------------------------------------------
// Kernel 3b: FAR attention. 128-thr blocks = 2 waves splitting the far r-tiles
// of one 16-row q-tile (interleaved by pair). No w_s: rel_v edge rows are
// pre-folded into VT0/VT1. Outputs unnormalized O_far (fp32) + rowsum.
// Target 16 wg/CU x 2 waves = 32 waves/CU.
__global__ __launch_bounds__(128, 8) void attn_far_kernel(
    const __bf16* __restrict__ Qh, const __bf16* __restrict__ Kh,
    const __bf16* __restrict__ VT0, const __bf16* __restrict__ VT1,
    const _Float16* __restrict__ qrelG, const int* __restrict__ mask,
    float* __restrict__ OfarG, float* __restrict__ rsG)
{
    __shared__ __align__(16) __bf16 p_s[2][16][40];
    __shared__ float ored[16][68];
    __shared__ float osum[16];

    const int tid = threadIdx.x, lane = tid & 63, wid = tid >> 6;
    const int quad = lane >> 4, l15 = lane & 15;
    const int bh = blockIdx.y, b = bh >> 4;
    const int t0 = blockIdx.x, l0 = t0 * 16;

    const __bf16* Qbase = Qh  + (size_t)bh * 65536;
    const __bf16* Kbase = Kh  + (size_t)bh * 65536;
    const __bf16* V0    = VT0 + (size_t)bh * 65536;
    const __bf16* V1    = VT1 + (size_t)bh * 65536;
    const _Float16* qr  = qrelG + ((size_t)bh * 1024 + l0) * 272;

    const bf16x8_t aq0 = *(const bf16x8_t*)(Qbase + (l0 + l15) * 64 + quad * 8);
    const bf16x8_t aq1 = *(const bf16x8_t*)(Qbase + (l0 + l15) * 64 + 32 + quad * 8);

    float c0[4], c1[4];
    #pragma unroll
    for (int v = 0; v < 4; ++v) {
        c0[v] = (float)qr[(quad * 4 + v) * 272 + 0];
        c1[v] = (float)qr[(quad * 4 + v) * 272 + 256];
    }

    const int nlo = t0 > 8 ? t0 - 8 : 0;        // tiles rbase <= l0-144
    const int nhi = t0 < 55 ? 55 - t0 : 0;      // tiles rbase >= l0+144
    const int nfar = nlo + nhi;
    const int npairs = (nfar + 1) >> 1;

    f32x4_t o[4];
    #pragma unroll
    for (int dt = 0; dt < 4; ++dt) o[dt] = (f32x4_t){0.f, 0.f, 0.f, 0.f};
    float rowsum[4] = {0.f, 0.f, 0.f, 0.f};

    for (int i = wid; i < npairs; i += 2) {
        const int ta = 2 * i, tb = 2 * i + 1;
        const bool hasB = (tb < nfar);
        int rbA, rbB;
        const __bf16 *VA, *VB;
        {   // slot 0
            const bool isLo = (ta < nlo);
            const int rb = (isLo ? ta : t0 + 9 + (ta - nlo)) * 16;
            rbA = rb; VA = isLo ? V0 : V1;
            const int r = rb + l15;
            const bf16x8_t kb0 = *(const bf16x8_t*)(Kbase + r * 64 + quad * 8);
            const bf16x8_t kb1 = *(const bf16x8_t*)(Kbase + r * 64 + 32 + quad * 8);
            f32x4_t s = (f32x4_t){0.f, 0.f, 0.f, 0.f};
            s = MFMA16(aq0, kb0, s);
            s = MFMA16(aq1, kb1, s);
            const float madd = (mask[b * 1024 + r] == 0) ? -1.0e9f : 0.f;
            #pragma unroll
            for (int v = 0; v < 4; ++v) {
                const float cc = isLo ? c0[v] : c1[v];
                const float p = __expf(fmaf(s[v], SCALE, cc) + madd);
                const __bf16 pb = (__bf16)p;
                rowsum[v] += (float)pb;
                p_s[wid][quad * 4 + v][l15] = pb;
            }
        }
        if (hasB) {   // slot 1
            const bool isLo = (tb < nlo);
            const int rb = (isLo ? tb : t0 + 9 + (tb - nlo)) * 16;
            rbB = rb; VB = isLo ? V0 : V1;
            const int r = rb + l15;
            const bf16x8_t kb0 = *(const bf16x8_t*)(Kbase + r * 64 + quad * 8);
            const bf16x8_t kb1 = *(const bf16x8_t*)(Kbase + r * 64 + 32 + quad * 8);
            f32x4_t s = (f32x4_t){0.f, 0.f, 0.f, 0.f};
            s = MFMA16(aq0, kb0, s);
            s = MFMA16(aq1, kb1, s);
            const float madd = (mask[b * 1024 + r] == 0) ? -1.0e9f : 0.f;
            #pragma unroll
            for (int v = 0; v < 4; ++v) {
                const float cc = isLo ? c0[v] : c1[v];
                const float p = __expf(fmaf(s[v], SCALE, cc) + madd);
                const __bf16 pb = (__bf16)p;
                rowsum[v] += (float)pb;
                p_s[wid][quad * 4 + v][16 + l15] = pb;
            }
        } else {
            rbB = rbA; VB = VA;
            #pragma unroll
            for (int v = 0; v < 4; ++v)
                p_s[wid][quad * 4 + v][16 + l15] = (__bf16)0.f;
        }
        // PV over 32 r (both slots), wave-private LDS round-trip
        const bf16x8_t pa = *(const bf16x8_t*)(&p_s[wid][l15][quad * 8]);
        const __bf16* Vsel = (quad < 2) ? VA : VB;
        const int roff = (quad < 2) ? (rbA + quad * 8) : (rbB + (quad - 2) * 8);
        #pragma unroll
        for (int dt = 0; dt < 4; ++dt) {
            const bf16x8_t vb =
                *(const bf16x8_t*)(Vsel + (dt * 16 + l15) * 1024 + roff);
            o[dt] = MFMA16(pa, vb, o[dt]);
        }
    }

    #pragma unroll
    for (int v = 0; v < 4; ++v)
        #pragma unroll
        for (int mm = 1; mm < 16; mm <<= 1)
            rowsum[v] += __shfl_xor(rowsum[v], mm, 64);

    if (wid == 1) {
        #pragma unroll
        for (int dt = 0; dt < 4; ++dt)
            #pragma unroll
            for (int v = 0; v < 4; ++v)
                ored[quad * 4 + v][dt * 16 + l15] = o[dt][v];
        if (l15 == 0) {
            #pragma unroll
            for (int v = 0; v < 4; ++v) osum[quad * 4 + v] = rowsum[v];
        }
    }
    __syncthreads();
    if (wid == 0) {
        float* Od = OfarG + ((size_t)bh * 1024 + l0) * 64;
        #pragma unroll
        for (int dt = 0; dt < 4; ++dt)
            #pragma unroll
            for (int v = 0; v < 4; ++v)
                Od[(quad * 4 + v) * 64 + dt * 16 + l15]
                    = o[dt][v] + ored[quad * 4 + v][dt * 16 + l15];
        if (l15 == 0) {
            #pragma unroll
            for (int v = 0; v < 4; ++v)
                rsG[bh * 1024 + l0 + quad * 4 + v] = rowsum[v] + osum[quad * 4 + v];
        }
    }
}

// ---------------------------------------------------------------------------
// Kernel 4: BAND attention. One wave per q-tile, 17 band r-tiles, w_s LDS
// histogram + w @ rel_v, merges O_far, normalizes, writes ctx. Zero barriers.
__global__ __launch_bounds__(64, 4) void attn_band_kernel(
    const __bf16* __restrict__ Qh, const __bf16* __restrict__ Kh,
    const __bf16* __restrict__ VhT, const _Float16* __restrict__ qrelG,
    const __bf16* __restrict__ rvT, const int* __restrict__ mask,
    const float* __restrict__ OfarG, const float* __restrict__ rsG,
    __bf16* __restrict__ ctx)
{
    __shared__ __align__(16) __bf16 w_s[16][288];
    __shared__ __align__(16) __bf16 p_s[16][40];

    const int lane = threadIdx.x & 63;
    const int quad = lane >> 4, l15 = lane & 15;
    const int bh = blockIdx.y, b = bh >> 4;
    const int t0 = blockIdx.x, l0 = t0 * 16;

    const __bf16* Qbase = Qh  + (size_t)bh * 65536;
    const __bf16* Kbase = Kh  + (size_t)bh * 65536;
    const __bf16* Vbase = VhT + (size_t)bh * 65536;
    const _Float16* qr  = qrelG + ((size_t)bh * 1024 + l0) * 272;

    {   // zero w_s (16x288 bf16 = 9216 B = 576 uint4)
        uint4* wz = (uint4*)&w_s[0][0];
        for (int t = lane; t < 576; t += 64) wz[t] = (uint4){0u, 0u, 0u, 0u};
    }

    const bf16x8_t aq0 = *(const bf16x8_t*)(Qbase + (l0 + l15) * 64 + quad * 8);
    const bf16x8_t aq1 = *(const bf16x8_t*)(Qbase + (l0 + l15) * 64 + 32 + quad * 8);

    const int tstart = t0 > 8 ? t0 - 8 : 0;
    const int tend   = t0 < 55 ? t0 + 8 : 63;
    const int nb = tend - tstart + 1;

    f32x4_t o[4];
    #pragma unroll
    for (int dt = 0; dt < 4; ++dt) o[dt] = (f32x4_t){0.f, 0.f, 0.f, 0.f};
    float rowsum[4] = {0.f, 0.f, 0.f, 0.f};
    float e0[4] = {0.f, 0.f, 0.f, 0.f};
    float e1[4] = {0.f, 0.f, 0.f, 0.f};

    for (int m = 0; m < nb; m += 2) {
        const int rbA = (tstart + m) * 16;
        const bool hasB = (m + 1 < nb);
        const int rbB = hasB ? rbA + 16 : rbA;
        #pragma unroll
        for (int slot = 0; slot < 2; ++slot) {
            if (slot == 1 && !hasB) {
                #pragma unroll
                for (int v = 0; v < 4; ++v)
                    p_s[quad * 4 + v][16 + l15] = (__bf16)0.f;
                break;
            }
            const int rb = slot ? rbB : rbA;
            const int r = rb + l15;
            const bf16x8_t kb0 = *(const bf16x8_t*)(Kbase + r * 64 + quad * 8);
            const bf16x8_t kb1 = *(const bf16x8_t*)(Kbase + r * 64 + 32 + quad * 8);
            f32x4_t s = (f32x4_t){0.f, 0.f, 0.f, 0.f};
            s = MFMA16(aq0, kb0, s);
            s = MFMA16(aq1, kb1, s);
            const float madd = (mask[b * 1024 + r] == 0) ? -1.0e9f : 0.f;
            #pragma unroll
            for (int v = 0; v < 4; ++v) {
                const int lrow = quad * 4 + v;
                const int dd = r - (l0 + lrow);
                int j = dd + 128; j = j < 0 ? 0 : (j > 256 ? 256 : j);
                const float bias = (float)qr[lrow * 272 + j];
                const float p = __expf(fmaf(s[v], SCALE, bias) + madd);
                const __bf16 pb = (__bf16)p;
                const float pf = (float)pb;
                rowsum[v] += pf;
                p_s[lrow][slot * 16 + l15] = pb;
                if (j == 0)        e0[v] += pf;
                else if (j == 256) e1[v] += pf;
                else               w_s[lrow][j] = pb;
            }
        }
        const bf16x8_t pa = *(const bf16x8_t*)(&p_s[l15][quad * 8]);
        const int roff = (quad < 2) ? (rbA + quad * 8) : (rbB + (quad - 2) * 8);
        #pragma unroll
        for (int dt = 0; dt < 4; ++dt) {
            const bf16x8_t vb =
                *(const bf16x8_t*)(Vbase + (dt * 16 + l15) * 1024 + roff);
            o[dt] = MFMA16(pa, vb, o[dt]);
        }
    }

    #pragma unroll
    for (int v = 0; v < 4; ++v) {
        #pragma unroll
        for (int mm = 1; mm < 16; mm <<= 1) {
            rowsum[v] += __shfl_xor(rowsum[v], mm, 64);
            e0[v]     += __shfl_xor(e0[v], mm, 64);
            e1[v]     += __shfl_xor(e1[v], mm, 64);
        }
    }
    if (l15 == 0) {
        #pragma unroll
        for (int v = 0; v < 4; ++v) {
            w_s[quad * 4 + v][0]   = (__bf16)e0[v];
            w_s[quad * 4 + v][256] = (__bf16)e1[v];
        }
    }

    // O += w @ rel_v (band bins + band-internal edge hits)
    for (int kc = 0; kc < 9; ++kc) {
        const bf16x8_t wa = *(const bf16x8_t*)(&w_s[l15][kc * 32 + quad * 8]);
        #pragma unroll
        for (int dt = 0; dt < 4; ++dt) {
            const bf16x8_t rb =
                *(const bf16x8_t*)(rvT + (dt * 16 + l15) * 288 + kc * 32 + quad * 8);
            o[dt] = MFMA16(wa, rb, o[dt]);
        }
    }

    // merge O_far + rowsums, normalize, store ctx [b][s][h*64+d]
    float rinv[4];
    #pragma unroll
    for (int v = 0; v < 4; ++v)
        rinv[v] = 1.f / (rowsum[v] + rsG[bh * 1024 + l0 + quad * 4 + v]);
    const float* Od = OfarG + ((size_t)bh * 1024 + l0) * 64;
    const int h = bh & 15;
    #pragma unroll
    for (int dt = 0; dt < 4; ++dt)
        #pragma unroll
        for (int v = 0; v < 4; ++v) {
            const int lrow = quad * 4 + v;
            const float val = (o[dt][v] + Od[lrow * 64 + dt * 16 + l15]) * rinv[v];
            ctx[((size_t)b * 1024 + l0 + lrow) * 1024 + h * 64 + dt * 16 + l15]
                = (__bf16)val;
        }
}

// ---------------------------------------------------------------------------
extern "C" void kernel_launch(void* const* d_in, const int* in_sizes, int n_in,
                              void* d_out, int out_size, void* d_ws, size_t ws_size,
                              hipStream_t stream)
{
    const float* q    = (const float*)d_in[0];
    const float* k    = (const float*)d_in[1];
    const float* v    = (const float*)d_in[2];
    const int*   mask = (const int*)  d_in[3];
    const float* wq   = (const float*)d_in[4];
    const float* bq   = (const float*)d_in[5];
    const float* wk   = (const float*)d_in[6];
    const float* bk   = (const float*)d_in[7];
    const float* wv   = (const float*)d_in[8];
    const float* bv   = (const float*)d_in[9];
    const float* wo   = (const float*)d_in[10];
    const float* bo   = (const float*)d_in[11];
    const float* relk = (const float*)d_in[12];
    const float* relv = (const float*)d_in[13];

    // workspace layout (bf16 elements unless noted); ~111.5 MB total.
    // qrelG (fp16, 17,825,792 elems) overlays Xbf|Xqlo_gap|Wqlo (17,825,792
    // bf16 slots), all dead after gemm_qkv.
    __bf16* Xbf   = (__bf16*)d_ws;            // 12582912 (q,k,v inputs hi)
    __bf16* Xgap  = Xbf   + 12582912;         // 4194304 (dead; qrelG overlay pad)
    __bf16* Wqlo  = Xgap  + 4194304;          // 1048576 (wq residual)
    __bf16* Wall  = Wqlo  + 1048576;          // 4194304 (wq,wk,wv,wo hi)
    __bf16* QKVh  = Wall  + 4194304;          // 12582912 (Q, K, VT plain)
    __bf16* ctx   = QKVh  + 12582912;         // 4194304
    __bf16* relkp = ctx   + 4194304;          // 34816 (hi | lo)
    __bf16* rvT   = relkp + 34816;            // 18432
    __bf16* VT0   = rvT   + 18432;            // 4194304 (V^T + rel_v[0])
    __bf16* VT1   = VT0   + 4194304;          // 4194304 (V^T + rel_v[256])
    float*  OfarG = (float*)(VT1 + 4194304);  // 4194304 floats (unnormalized far O)
    float*  rsG   = OfarG + 4194304;          // 65536 floats (far rowsums)
    _Float16* qrelG = (_Float16*)d_ws;        // overlay, written after qkv

    cast_all_kernel<<<16419, 256, 0, stream>>>(q, k, v, wq, wk, wv, wo, relk, relv,
                                               Xbf, Wall, relkp, rvT, Wqlo);
    gemm_qkv_kernel<<<dim3(8, 32, 3), 256, 0, stream>>>(Xbf, Wall, Wqlo,
                                                        bq, bk, bv, relv,
                                                        QKVh, VT0, VT1);
    qrel_kernel<<<dim3(16, 64), 256, 0, stream>>>(QKVh, relkp, qrelG);
    attn_far_kernel<<<dim3(64, 64), 128, 0, stream>>>(QKVh, QKVh + 4194304,
                                                      VT0, VT1, qrelG, mask,
                                                      OfarG, rsG);
    attn_band_kernel<<<dim3(64, 64), 64, 0, stream>>>(QKVh, QKVh + 4194304,
                                                      QKVh + 2 * 4194304, qrelG,
                                                      rvT, mask, OfarG, rsG, ctx);
    gemm_out_kernel<<<dim3(8, 32, 1), 256, 0, stream>>>(ctx, Wall + 3 * 1048576,
                                                        bo, (float*)d_out);
}

// Round 6
// 472.164 us; speedup vs baseline: 1.0887x; 1.0887x over previous
//
#include <hip/hip_runtime.h>
#include <hip/hip_bf16.h>

// Problem constants
#define S_LEN  1024
#define DMODEL 1024
#define NHEADS 16
#define DK     64
#define SCALE  0.125f
// rel table: 257 rows; qrelG pitch 272; rvT pitch 288 (K-pad for 9x32 MFMA).
// Attention split: far tiles (whole 16x16 subtile clipped to rel row 0/256)
// use a rank-1 fp32 epilogue (e0*rel_v[0] + e1*rel_v[256]); 17 band tiles
// per q-tile use the LDS histogram w_s and w @ rel_v.
// Both attention kernels use an XCD-affine block swizzle: all 64 q-tiles of
// one bh land on one XCD so its K/V stay resident in that XCD's 4MB L2.

typedef __bf16 bf16x8_t __attribute__((ext_vector_type(8)));
typedef __bf16 bf16x4_t __attribute__((ext_vector_type(4)));
typedef float  f32x4_t  __attribute__((ext_vector_type(4)));

#define MFMA16(A, B, C) __builtin_amdgcn_mfma_f32_16x16x32_bf16((A), (B), (C), 0, 0, 0)

__device__ __forceinline__ void async16(const void* g, void* l) {
    __builtin_amdgcn_global_load_lds(
        (const __attribute__((address_space(1))) unsigned int*)g,
        (__attribute__((address_space(3))) unsigned int*)l, 16, 0, 0);
}

// ---------------------------------------------------------------------------
// Kernel 1: cast inputs to bf16 + build padded rel tables.
__global__ __launch_bounds__(256) void cast_all_kernel(
    const float* __restrict__ q, const float* __restrict__ k, const float* __restrict__ v,
    const float* __restrict__ wq, const float* __restrict__ wk,
    const float* __restrict__ wv, const float* __restrict__ wo,
    const float* __restrict__ relk, const float* __restrict__ relv,
    __bf16* __restrict__ Xbf, __bf16* __restrict__ Wall,
    __bf16* __restrict__ relkp, __bf16* __restrict__ rvT,
    __bf16* __restrict__ Wqlo)
{
    const long i = (long)blockIdx.x * 256 + threadIdx.x;   // vec4 index
    if (i < 3145728) {                       // X region
        const int z   = (int)(i >> 20);
        const long rem = i & 1048575;
        const float4 s = ((const float4*)(z == 0 ? q : (z == 1 ? k : v)))[rem];
        bf16x4_t h;
        h[0] = (__bf16)s.x; h[1] = (__bf16)s.y; h[2] = (__bf16)s.z; h[3] = (__bf16)s.w;
        *(bf16x4_t*)(Xbf + ((size_t)z << 22) + rem * 4) = h;
    } else if (i < 3145728 + 1048576) {      // W region
        const long wi = i - 3145728;
        const int z   = (int)(wi >> 18);
        const long rem = wi & 262143;
        const float* src = (z == 0) ? wq : (z == 1) ? wk : (z == 2) ? wv : wo;
        const float4 s = ((const float4*)src)[rem];
        const float xs[4] = {s.x, s.y, s.z, s.w};
        bf16x4_t h;
        #pragma unroll
        for (int t = 0; t < 4; ++t) h[t] = (__bf16)xs[t];
        *(bf16x4_t*)(Wall + ((size_t)z << 20) + rem * 4) = h;
        if (z == 0) {
            bf16x4_t l;
            #pragma unroll
            for (int t = 0; t < 4; ++t) l[t] = (__bf16)(xs[t] - (float)h[t]);
            *(bf16x4_t*)(Wqlo + rem * 4) = l;
        }
    } else if (i < 3145728 + 1048576 + 4352) {   // relk hi+lo (272 rows x 64)
        const long ri = i - (3145728 + 1048576);
        const int j  = (int)(ri >> 4);
        const int d4 = (int)(ri & 15) * 4;
        bf16x4_t h, l;
        if (j < 257) {
            const float4 s = *(const float4*)(relk + j * 64 + d4);
            const float xs[4] = {s.x, s.y, s.z, s.w};
            #pragma unroll
            for (int t = 0; t < 4; ++t) {
                h[t] = (__bf16)xs[t];
                l[t] = (__bf16)(xs[t] - (float)h[t]);
            }
        } else {
            #pragma unroll
            for (int t = 0; t < 4; ++t) { h[t] = (__bf16)0.f; l[t] = (__bf16)0.f; }
        }
        *(bf16x4_t*)(relkp + j * 64 + d4) = h;
        *(bf16x4_t*)(relkp + 17408 + j * 64 + d4) = l;
    } else if (i < 3145728 + 1048576 + 4352 + 4608) { // rvT: [64][288], rvT[d][j]=rel_v[j][d]
        const long ri = i - (3145728 + 1048576 + 4352);
        const int d  = (int)(ri / 72);
        const int j4 = (int)(ri % 72) * 4;
        bf16x4_t o;
        #pragma unroll
        for (int t = 0; t < 4; ++t) {
            const int j = j4 + t;
            o[t] = (j < 257) ? (__bf16)relv[j * 64 + d] : (__bf16)0.f;
        }
        *(bf16x4_t*)(rvT + d * 288 + j4) = o;
    }
}

// ---------------------------------------------------------------------------
// Shared 128x128 tile GEMM core: acc += A(128xK) @ W(128xK)^T, K=1024, BK=32.
__device__ __forceinline__ void gemm128_core(
    const __bf16* __restrict__ A, const __bf16* __restrict__ W,
    __bf16* As, __bf16* Ws, f32x4_t acc[4][4])
{
    const int tid  = threadIdx.x;
    const int lane = tid & 63;
    const int quad = lane >> 4;
    const int l15  = lane & 15;
    const int wid  = tid >> 6;
    const int wm = wid >> 1, wn = wid & 1;

    for (int kt = 0; kt < 32; ++kt) {
        #pragma unroll
        for (int r = 0; r < 2; ++r) {
            const int c = r * 256 + tid;        // 512 chunks of 16B per tile
            const int row = c >> 2, kb = c & 3;
            async16(A + row * 1024 + kt * 32 + kb * 8, As + c * 8);
            async16(W + row * 1024 + kt * 32 + kb * 8, Ws + c * 8);
        }
        __syncthreads();                        // drains vmcnt for global_load_lds
        bf16x8_t af[4], wf[4];
        #pragma unroll
        for (int i = 0; i < 4; ++i) {
            af[i] = *(const bf16x8_t*)(As + (wm * 64 + i * 16 + l15) * 32 + quad * 8);
            wf[i] = *(const bf16x8_t*)(Ws + (wn * 64 + i * 16 + l15) * 32 + quad * 8);
        }
        #pragma unroll
        for (int i = 0; i < 4; ++i)
            #pragma unroll
            for (int j = 0; j < 4; ++j)
                acc[i][j] = MFMA16(af[i], wf[j], acc[i][j]);
        __syncthreads();
    }
}

// ---------------------------------------------------------------------------
// Kernel 2: QKV projections. z=0:Q (W hi+lo for precision), z=1:K [bh][s][d];
// z=2:V transposed [bh][d][s].
__global__ __launch_bounds__(256) void gemm_qkv_kernel(
    const __bf16* __restrict__ Xbf, const __bf16* __restrict__ Wall,
    const __bf16* __restrict__ Wqlo,
    const float* __restrict__ bq, const float* __restrict__ bk, const float* __restrict__ bv,
    __bf16* __restrict__ QKVh)
{
    __shared__ __bf16 As[4096], Ws[4096];
    const int z = blockIdx.z;
    const __bf16* A = Xbf + (size_t)z * 4194304 + (size_t)blockIdx.y * 131072;
    const __bf16* W = Wall + (size_t)z * 1048576 + (size_t)blockIdx.x * 131072;
    f32x4_t acc[4][4];
    #pragma unroll
    for (int i = 0; i < 4; ++i)
        #pragma unroll
        for (int j = 0; j < 4; ++j)
            acc[i][j] = (f32x4_t){0.f, 0.f, 0.f, 0.f};

    gemm128_core(A, W, As, Ws, acc);
    if (z == 0)   // Q = Xhi*(Whi+Wlo)
        gemm128_core(A, Wqlo + (size_t)blockIdx.x * 131072, As, Ws, acc);

    const int tid = threadIdx.x, lane = tid & 63, quad = lane >> 4, l15 = lane & 15;
    const int wid = tid >> 6, wm = wid >> 1, wn = wid & 1;
    const int m0 = blockIdx.y * 128 + wm * 64;
    const int n0 = blockIdx.x * 128 + wn * 64;
    const float* bias = (z == 0) ? bq : ((z == 1) ? bk : bv);
    __bf16* dst = QKVh + (size_t)z * 4194304;

    if (z < 2) {
        #pragma unroll
        for (int j = 0; j < 4; ++j) {
            const int n = n0 + j * 16 + l15;
            const float bn = bias[n];
            #pragma unroll
            for (int i = 0; i < 4; ++i) {
                #pragma unroll
                for (int v = 0; v < 4; ++v) {
                    const int m = m0 + i * 16 + quad * 4 + v;
                    dst[((((m >> 10) * 16 + (n >> 6)) << 16)) + ((m & 1023) << 6) + (n & 63)]
                        = (__bf16)(acc[i][j][v] + bn);
                }
            }
        }
    } else {
        #pragma unroll
        for (int j = 0; j < 4; ++j) {
            const int n = n0 + j * 16 + l15;
            const float bn = bias[n];
            #pragma unroll
            for (int i = 0; i < 4; ++i) {
                const int m = m0 + i * 16 + quad * 4;
                bf16x4_t pk;
                #pragma unroll
                for (int v = 0; v < 4; ++v) pk[v] = (__bf16)(acc[i][j][v] + bn);
                *(bf16x4_t*)(dst + (((size_t)((m >> 10) * 16 + (n >> 6))) << 16)
                                 + ((n & 63) << 10) + (m & 1023)) = pk;
            }
        }
    }
}

// ---------------------------------------------------------------------------
// Kernel 5: output projection, fp32 epilogue straight to d_out.
__global__ __launch_bounds__(256) void gemm_out_kernel(
    const __bf16* __restrict__ ctx, const __bf16* __restrict__ Wo,
    const float* __restrict__ bo, float* __restrict__ out)
{
    __shared__ __bf16 As[4096], Ws[4096];
    const __bf16* A = ctx + (size_t)blockIdx.y * 131072;
    const __bf16* W = Wo + (size_t)blockIdx.x * 131072;
    f32x4_t acc[4][4];
    #pragma unroll
    for (int i = 0; i < 4; ++i)
        #pragma unroll
        for (int j = 0; j < 4; ++j)
            acc[i][j] = (f32x4_t){0.f, 0.f, 0.f, 0.f};
    gemm128_core(A, W, As, Ws, acc);

    const int tid = threadIdx.x, lane = tid & 63, quad = lane >> 4, l15 = lane & 15;
    const int wid = tid >> 6, wm = wid >> 1, wn = wid & 1;
    const int m0 = blockIdx.y * 128 + wm * 64;
    const int n0 = blockIdx.x * 128 + wn * 64;
    #pragma unroll
    for (int j = 0; j < 4; ++j) {
        const int n = n0 + j * 16 + l15;
        const float bn = bo[n];
        #pragma unroll
        for (int i = 0; i < 4; ++i)
            #pragma unroll
            for (int v = 0; v < 4; ++v) {
                const int m = m0 + i * 16 + quad * 4 + v;
                out[(size_t)m * 1024 + n] = acc[i][j][v] + bn;
            }
    }
}

// ---------------------------------------------------------------------------
// Kernel 3a: qrel GEMM. qrelG[bh][l][j] = Q[bh,l]·rel_k[j] (hi+lo), fp16 out.
__global__ __launch_bounds__(256) void qrel_kernel(
    const __bf16* __restrict__ Qh, const __bf16* __restrict__ relkp,
    _Float16* __restrict__ qrelG)
{
    const int tid = threadIdx.x, lane = tid & 63, wid = tid >> 6;
    const int quad = lane >> 4, l15 = lane & 15;
    const int bh = blockIdx.y;
    const int l0 = blockIdx.x * 64 + wid * 16;
    const __bf16* Qbase = Qh + (size_t)bh * 65536;
    const __bf16* relk_hi = relkp;
    const __bf16* relk_lo = relkp + 17408;
    const bf16x8_t aq0 = *(const bf16x8_t*)(Qbase + (l0 + l15) * 64 + quad * 8);
    const bf16x8_t aq1 = *(const bf16x8_t*)(Qbase + (l0 + l15) * 64 + 32 + quad * 8);
    _Float16* out = qrelG + ((size_t)bh * 1024 + l0) * 272;
    for (int nt = 0; nt < 17; ++nt) {
        const int j = nt * 16 + l15;
        const bf16x8_t h0  = *(const bf16x8_t*)(relk_hi + j * 64 + quad * 8);
        const bf16x8_t h1  = *(const bf16x8_t*)(relk_hi + j * 64 + 32 + quad * 8);
        const bf16x8_t lo0 = *(const bf16x8_t*)(relk_lo + j * 64 + quad * 8);
        const bf16x8_t lo1 = *(const bf16x8_t*)(relk_lo + j * 64 + 32 + quad * 8);
        f32x4_t c = (f32x4_t){0.f, 0.f, 0.f, 0.f};
        c = MFMA16(aq0, lo0, c);
        c = MFMA16(aq1, lo1, c);
        c = MFMA16(aq0, h0, c);
        c = MFMA16(aq1, h1, c);
        #pragma unroll
        for (int v = 0; v < 4; ++v)
            out[(quad * 4 + v) * 272 + j] = (_Float16)c[v];
    }
}

// ---------------------------------------------------------------------------
// Kernel 3b: FAR attention. 128-thr blocks = 2 waves splitting the far r-tiles
// of one 16-row q-tile. Every far prob has rel bias row 0 (lo) or 256 (hi),
// so rel_v enters as a rank-1 fp32 term: O += e0*rel_v[0] + e1*rel_v[256],
// and rowsum = e0+e1. Outputs unnormalized O_far (fp32) + rowsum.
__global__ __launch_bounds__(128, 8) void attn_far_kernel(
    const __bf16* __restrict__ Qh, const __bf16* __restrict__ Kh,
    const __bf16* __restrict__ VhT, const _Float16* __restrict__ qrelG,
    const int* __restrict__ mask, const float* __restrict__ relv,
    float* __restrict__ OfarG, float* __restrict__ rsG)
{
    __shared__ __align__(16) __bf16 p_s[2][16][40];
    __shared__ float ored[16][68];
    __shared__ float e0s[16], e1s[16];

    const int tid = threadIdx.x, lane = tid & 63, wid = tid >> 6;
    const int quad = lane >> 4, l15 = lane & 15;
    // XCD-affine swizzle: all q-tiles of one bh on one XCD
    const int lin = blockIdx.x;
    const int slot = lin >> 3;
    const int bh = (lin & 7) + 8 * (slot >> 6);
    const int t0 = slot & 63, l0 = t0 * 16;
    const int b = bh >> 4;

    const __bf16* Qbase = Qh  + (size_t)bh * 65536;
    const __bf16* Kbase = Kh  + (size_t)bh * 65536;
    const __bf16* Vbase = VhT + (size_t)bh * 65536;
    const _Float16* qr  = qrelG + ((size_t)bh * 1024 + l0) * 272;

    const bf16x8_t aq0 = *(const bf16x8_t*)(Qbase + (l0 + l15) * 64 + quad * 8);
    const bf16x8_t aq1 = *(const bf16x8_t*)(Qbase + (l0 + l15) * 64 + 32 + quad * 8);

    float c0[4], c1[4];
    #pragma unroll
    for (int v = 0; v < 4; ++v) {
        c0[v] = (float)qr[(quad * 4 + v) * 272 + 0];
        c1[v] = (float)qr[(quad * 4 + v) * 272 + 256];
    }

    const int nlo = t0 > 8 ? t0 - 8 : 0;        // tiles rbase <= l0-144
    const int nhi = t0 < 55 ? 55 - t0 : 0;      // tiles rbase >= l0+144
    const int nfar = nlo + nhi;
    const int npairs = (nfar + 1) >> 1;

    f32x4_t o[4];
    #pragma unroll
    for (int dt = 0; dt < 4; ++dt) o[dt] = (f32x4_t){0.f, 0.f, 0.f, 0.f};
    float e0[4] = {0.f, 0.f, 0.f, 0.f};
    float e1[4] = {0.f, 0.f, 0.f, 0.f};

    for (int i = wid; i < npairs; i += 2) {
        const int ta = 2 * i, tb = 2 * i + 1;
        const bool hasB = (tb < nfar);
        int rbA, rbB;
        {   // slot 0
            const bool isLo = (ta < nlo);
            const int rb = (isLo ? ta : t0 + 9 + (ta - nlo)) * 16;
            rbA = rb;
            const int r = rb + l15;
            const bf16x8_t kb0 = *(const bf16x8_t*)(Kbase + r * 64 + quad * 8);
            const bf16x8_t kb1 = *(const bf16x8_t*)(Kbase + r * 64 + 32 + quad * 8);
            f32x4_t s = (f32x4_t){0.f, 0.f, 0.f, 0.f};
            s = MFMA16(aq0, kb0, s);
            s = MFMA16(aq1, kb1, s);
            const float madd = (mask[b * 1024 + r] == 0) ? -1.0e9f : 0.f;
            #pragma unroll
            for (int v = 0; v < 4; ++v) {
                const float cc = isLo ? c0[v] : c1[v];
                const float p = __expf(fmaf(s[v], SCALE, cc) + madd);
                const __bf16 pb = (__bf16)p;
                const float pf = (float)pb;
                if (isLo) e0[v] += pf; else e1[v] += pf;
                p_s[wid][quad * 4 + v][l15] = pb;
            }
        }
        if (hasB) {   // slot 1
            const bool isLo = (tb < nlo);
            const int rb = (isLo ? tb : t0 + 9 + (tb - nlo)) * 16;
            rbB = rb;
            const int r = rb + l15;
            const bf16x8_t kb0 = *(const bf16x8_t*)(Kbase + r * 64 + quad * 8);
            const bf16x8_t kb1 = *(const bf16x8_t*)(Kbase + r * 64 + 32 + quad * 8);
            f32x4_t s = (f32x4_t){0.f, 0.f, 0.f, 0.f};
            s = MFMA16(aq0, kb0, s);
            s = MFMA16(aq1, kb1, s);
            const float madd = (mask[b * 1024 + r] == 0) ? -1.0e9f : 0.f;
            #pragma unroll
            for (int v = 0; v < 4; ++v) {
                const float cc = isLo ? c0[v] : c1[v];
                const float p = __expf(fmaf(s[v], SCALE, cc) + madd);
                const __bf16 pb = (__bf16)p;
                const float pf = (float)pb;
                if (isLo) e0[v] += pf; else e1[v] += pf;
                p_s[wid][quad * 4 + v][16 + l15] = pb;
            }
        } else {
            rbB = rbA;
            #pragma unroll
            for (int v = 0; v < 4; ++v)
                p_s[wid][quad * 4 + v][16 + l15] = (__bf16)0.f;
        }
        // PV over both slots, wave-private LDS round-trip
        const bf16x8_t pa = *(const bf16x8_t*)(&p_s[wid][l15][quad * 8]);
        const int roff = (quad < 2) ? (rbA + quad * 8) : (rbB + (quad - 2) * 8);
        #pragma unroll
        for (int dt = 0; dt < 4; ++dt) {
            const bf16x8_t vb =
                *(const bf16x8_t*)(Vbase + (dt * 16 + l15) * 1024 + roff);
            o[dt] = MFMA16(pa, vb, o[dt]);
        }
    }

    #pragma unroll
    for (int v = 0; v < 4; ++v)
        #pragma unroll
        for (int mm = 1; mm < 16; mm <<= 1) {
            e0[v] += __shfl_xor(e0[v], mm, 64);
            e1[v] += __shfl_xor(e1[v], mm, 64);
        }

    if (wid == 1) {
        #pragma unroll
        for (int dt = 0; dt < 4; ++dt)
            #pragma unroll
            for (int v = 0; v < 4; ++v)
                ored[quad * 4 + v][dt * 16 + l15] = o[dt][v];
        if (l15 == 0) {
            #pragma unroll
            for (int v = 0; v < 4; ++v) {
                e0s[quad * 4 + v] = e0[v];
                e1s[quad * 4 + v] = e1[v];
            }
        }
    }
    __syncthreads();
    if (wid == 0) {
        float* Od = OfarG + ((size_t)bh * 1024 + l0) * 64;
        #pragma unroll
        for (int dt = 0; dt < 4; ++dt) {
            const int d = dt * 16 + l15;
            const float rv0   = relv[d];             // rel_v[0][d]
            const float rv256 = relv[256 * 64 + d];  // rel_v[256][d]
            #pragma unroll
            for (int v = 0; v < 4; ++v) {
                const int row = quad * 4 + v;
                const float e0t = e0[v] + e0s[row];
                const float e1t = e1[v] + e1s[row];
                Od[row * 64 + d] = o[dt][v] + ored[row][d]
                                 + e0t * rv0 + e1t * rv256;
            }
        }
        if (l15 == 0) {
            #pragma unroll
            for (int v = 0; v < 4; ++v) {
                const int row = quad * 4 + v;
                rsG[bh * 1024 + l0 + row] = e0[v] + e0s[row] + e1[v] + e1s[row];
            }
        }
    }
}

// ---------------------------------------------------------------------------
// Kernel 4: BAND attention. One wave per q-tile, 17 band r-tiles, w_s LDS
// histogram + w @ rel_v, merges O_far, normalizes, writes ctx. Zero barriers.
__global__ __launch_bounds__(64, 4) void attn_band_kernel(
    const __bf16* __restrict__ Qh, const __bf16* __restrict__ Kh,
    const __bf16* __restrict__ VhT, const _Float16* __restrict__ qrelG,
    const __bf16* __restrict__ rvT, const int* __restrict__ mask,
    const float* __restrict__ OfarG, const float* __restrict__ rsG,
    __bf16* __restrict__ ctx)
{
    __shared__ __align__(16) __bf16 w_s[16][288];
    __shared__ __align__(16) __bf16 p_s[16][40];

    const int lane = threadIdx.x & 63;
    const int quad = lane >> 4, l15 = lane & 15;
    // XCD-affine swizzle (match attn_far)
    const int lin = blockIdx.x;
    const int slot = lin >> 3;
    const int bh = (lin & 7) + 8 * (slot >> 6);
    const int t0 = slot & 63, l0 = t0 * 16;
    const int b = bh >> 4;

    const __bf16* Qbase = Qh  + (size_t)bh * 65536;
    const __bf16* Kbase = Kh  + (size_t)bh * 65536;
    const __bf16* Vbase = VhT + (size_t)bh * 65536;
    const _Float16* qr  = qrelG + ((size_t)bh * 1024 + l0) * 272;

    {   // zero w_s (16x288 bf16 = 9216 B = 576 uint4)
        uint4* wz = (uint4*)&w_s[0][0];
        for (int t = lane; t < 576; t += 64) wz[t] = (uint4){0u, 0u, 0u, 0u};
    }

    const bf16x8_t aq0 = *(const bf16x8_t*)(Qbase + (l0 + l15) * 64 + quad * 8);
    const bf16x8_t aq1 = *(const bf16x8_t*)(Qbase + (l0 + l15) * 64 + 32 + quad * 8);

    const int tstart = t0 > 8 ? t0 - 8 : 0;
    const int tend   = t0 < 55 ? t0 + 8 : 63;
    const int nb = tend - tstart + 1;

    f32x4_t o[4];
    #pragma unroll
    for (int dt = 0; dt < 4; ++dt) o[dt] = (f32x4_t){0.f, 0.f, 0.f, 0.f};
    float rowsum[4] = {0.f, 0.f, 0.f, 0.f};
    float e0[4] = {0.f, 0.f, 0.f, 0.f};
    float e1[4] = {0.f, 0.f, 0.f, 0.f};

    for (int m = 0; m < nb; m += 2) {
        const int rbA = (tstart + m) * 16;
        const bool hasB = (m + 1 < nb);
        const int rbB = hasB ? rbA + 16 : rbA;
        #pragma unroll
        for (int slotn = 0; slotn < 2; ++slotn) {
            if (slotn == 1 && !hasB) {
                #pragma unroll
                for (int v = 0; v < 4; ++v)
                    p_s[quad * 4 + v][16 + l15] = (__bf16)0.f;
                break;
            }
            const int rb = slotn ? rbB : rbA;
            const int r = rb + l15;
            const bf16x8_t kb0 = *(const bf16x8_t*)(Kbase + r * 64 + quad * 8);
            const bf16x8_t kb1 = *(const bf16x8_t*)(Kbase + r * 64 + 32 + quad * 8);
            f32x4_t s = (f32x4_t){0.f, 0.f, 0.f, 0.f};
            s = MFMA16(aq0, kb0, s);
            s = MFMA16(aq1, kb1, s);
            const float madd = (mask[b * 1024 + r] == 0) ? -1.0e9f : 0.f;
            #pragma unroll
            for (int v = 0; v < 4; ++v) {
                const int lrow = quad * 4 + v;
                const int dd = r - (l0 + lrow);
                int j = dd + 128; j = j < 0 ? 0 : (j > 256 ? 256 : j);
                const float bias = (float)qr[lrow * 272 + j];
                const float p = __expf(fmaf(s[v], SCALE, bias) + madd);
                const __bf16 pb = (__bf16)p;
                const float pf = (float)pb;
                rowsum[v] += pf;
                p_s[lrow][slotn * 16 + l15] = pb;
                if (j == 0)        e0[v] += pf;
                else if (j == 256) e1[v] += pf;
                else               w_s[lrow][j] = pb;
            }
        }
        const bf16x8_t pa = *(const bf16x8_t*)(&p_s[l15][quad * 8]);
        const int roff = (quad < 2) ? (rbA + quad * 8) : (rbB + (quad - 2) * 8);
        #pragma unroll
        for (int dt = 0; dt < 4; ++dt) {
            const bf16x8_t vb =
                *(const bf16x8_t*)(Vbase + (dt * 16 + l15) * 1024 + roff);
            o[dt] = MFMA16(pa, vb, o[dt]);
        }
    }

    #pragma unroll
    for (int v = 0; v < 4; ++v) {
        #pragma unroll
        for (int mm = 1; mm < 16; mm <<= 1) {
            rowsum[v] += __shfl_xor(rowsum[v], mm, 64);
            e0[v]     += __shfl_xor(e0[v], mm, 64);
            e1[v]     += __shfl_xor(e1[v], mm, 64);
        }
    }
    if (l15 == 0) {
        #pragma unroll
        for (int v = 0; v < 4; ++v) {
            w_s[quad * 4 + v][0]   = (__bf16)e0[v];
            w_s[quad * 4 + v][256] = (__bf16)e1[v];
        }
    }

    // O += w @ rel_v (band bins + band-internal edge hits)
    for (int kc = 0; kc < 9; ++kc) {
        const bf16x8_t wa = *(const bf16x8_t*)(&w_s[l15][kc * 32 + quad * 8]);
        #pragma unroll
        for (int dt = 0; dt < 4; ++dt) {
            const bf16x8_t rb =
                *(const bf16x8_t*)(rvT + (dt * 16 + l15) * 288 + kc * 32 + quad * 8);
            o[dt] = MFMA16(wa, rb, o[dt]);
        }
    }

    // merge O_far + rowsums, normalize, store ctx [b][s][h*64+d]
    float rinv[4];
    #pragma unroll
    for (int v = 0; v < 4; ++v)
        rinv[v] = 1.f / (rowsum[v] + rsG[bh * 1024 + l0 + quad * 4 + v]);
    const float* Od = OfarG + ((size_t)bh * 1024 + l0) * 64;
    const int h = bh & 15;
    #pragma unroll
    for (int dt = 0; dt < 4; ++dt)
        #pragma unroll
        for (int v = 0; v < 4; ++v) {
            const int lrow = quad * 4 + v;
            const float val = (o[dt][v] + Od[lrow * 64 + dt * 16 + l15]) * rinv[v];
            ctx[((size_t)b * 1024 + l0 + lrow) * 1024 + h * 64 + dt * 16 + l15]
                = (__bf16)val;
        }
}

// ---------------------------------------------------------------------------
extern "C" void kernel_launch(void* const* d_in, const int* in_sizes, int n_in,
                              void* d_out, int out_size, void* d_ws, size_t ws_size,
                              hipStream_t stream)
{
    const float* q    = (const float*)d_in[0];
    const float* k    = (const float*)d_in[1];
    const float* v    = (const float*)d_in[2];
    const int*   mask = (const int*)  d_in[3];
    const float* wq   = (const float*)d_in[4];
    const float* bq   = (const float*)d_in[5];
    const float* wk   = (const float*)d_in[6];
    const float* bk   = (const float*)d_in[7];
    const float* wv   = (const float*)d_in[8];
    const float* bv   = (const float*)d_in[9];
    const float* wo   = (const float*)d_in[10];
    const float* bo   = (const float*)d_in[11];
    const float* relk = (const float*)d_in[12];
    const float* relv = (const float*)d_in[13];

    // workspace layout (bf16 elements unless noted); ~94 MB total.
    // qrelG (fp16, 17,825,792 elems) overlays Xbf|Xgap|Wqlo, dead after qkv.
    __bf16* Xbf   = (__bf16*)d_ws;            // 12582912 (q,k,v inputs hi)
    __bf16* Xgap  = Xbf   + 12582912;         // 4194304 (dead; qrelG overlay pad)
    __bf16* Wqlo  = Xgap  + 4194304;          // 1048576 (wq residual)
    __bf16* Wall  = Wqlo  + 1048576;          // 4194304 (wq,wk,wv,wo hi)
    __bf16* QKVh  = Wall  + 4194304;          // 12582912 (Q, K, VT)
    __bf16* ctx   = QKVh  + 12582912;         // 4194304
    __bf16* relkp = ctx   + 4194304;          // 34816 (hi | lo)
    __bf16* rvT   = relkp + 34816;            // 18432
    float*  OfarG = (float*)(rvT + 18432);    // 4194304 floats (unnormalized far O)
    float*  rsG   = OfarG + 4194304;          // 65536 floats (far rowsums)
    _Float16* qrelG = (_Float16*)d_ws;        // overlay, written after qkv

    cast_all_kernel<<<16419, 256, 0, stream>>>(q, k, v, wq, wk, wv, wo, relk, relv,
                                               Xbf, Wall, relkp, rvT, Wqlo);
    gemm_qkv_kernel<<<dim3(8, 32, 3), 256, 0, stream>>>(Xbf, Wall, Wqlo,
                                                        bq, bk, bv, QKVh);
    qrel_kernel<<<dim3(16, 64), 256, 0, stream>>>(QKVh, relkp, qrelG);
    attn_far_kernel<<<4096, 128, 0, stream>>>(QKVh, QKVh + 4194304,
                                              QKVh + 2 * 4194304, qrelG, mask,
                                              relv, OfarG, rsG);
    attn_band_kernel<<<4096, 64, 0, stream>>>(QKVh, QKVh + 4194304,
                                              QKVh + 2 * 4194304, qrelG,
                                              rvT, mask, OfarG, rsG, ctx);
    gemm_out_kernel<<<dim3(8, 32, 1), 256, 0, stream>>>(ctx, Wall + 3 * 1048576,
                                                        bo, (float*)d_out);
}

// Round 7
// 350.392 us; speedup vs baseline: 1.4670x; 1.3475x over previous
//
#include <hip/hip_runtime.h>
#include <hip/hip_bf16.h>

// Problem constants
#define S_LEN  1024
#define DMODEL 1024
#define NHEADS 16
#define DK     64
#define SCALE  0.125f
// rel table: 257 rows; qrelG pitch 272; rvT pitch 288.
// V layout (global): pair-tiled [bh][r/32][d][r%32] -> each 32-k V tile is a
// contiguous 4KB block, enabling coalesced global_load_lds staging.
// attn_far: 256-thr blocks, 64 q-rows, K/V staged to LDS with XOR bank
// swizzle applied on the GLOBAL side of global_load_lds (LDS side is
// uniform-base + lane*16 and cannot scatter).

typedef __bf16 bf16x8_t __attribute__((ext_vector_type(8)));
typedef __bf16 bf16x4_t __attribute__((ext_vector_type(4)));
typedef float  f32x4_t  __attribute__((ext_vector_type(4)));

#define MFMA16(A, B, C) __builtin_amdgcn_mfma_f32_16x16x32_bf16((A), (B), (C), 0, 0, 0)

__device__ __forceinline__ void async16(const void* g, void* l) {
    __builtin_amdgcn_global_load_lds(
        (const __attribute__((address_space(1))) unsigned int*)g,
        (__attribute__((address_space(3))) unsigned int*)l, 16, 0, 0);
}

// ---------------------------------------------------------------------------
// Kernel 1: cast inputs to bf16 + build padded rel tables.
__global__ __launch_bounds__(256) void cast_all_kernel(
    const float* __restrict__ q, const float* __restrict__ k, const float* __restrict__ v,
    const float* __restrict__ wq, const float* __restrict__ wk,
    const float* __restrict__ wv, const float* __restrict__ wo,
    const float* __restrict__ relk, const float* __restrict__ relv,
    __bf16* __restrict__ Xbf, __bf16* __restrict__ Wall,
    __bf16* __restrict__ relkp, __bf16* __restrict__ rvT,
    __bf16* __restrict__ Wqlo)
{
    const long i = (long)blockIdx.x * 256 + threadIdx.x;   // vec4 index
    if (i < 3145728) {                       // X region
        const int z   = (int)(i >> 20);
        const long rem = i & 1048575;
        const float4 s = ((const float4*)(z == 0 ? q : (z == 1 ? k : v)))[rem];
        bf16x4_t h;
        h[0] = (__bf16)s.x; h[1] = (__bf16)s.y; h[2] = (__bf16)s.z; h[3] = (__bf16)s.w;
        *(bf16x4_t*)(Xbf + ((size_t)z << 22) + rem * 4) = h;
    } else if (i < 3145728 + 1048576) {      // W region
        const long wi = i - 3145728;
        const int z   = (int)(wi >> 18);
        const long rem = wi & 262143;
        const float* src = (z == 0) ? wq : (z == 1) ? wk : (z == 2) ? wv : wo;
        const float4 s = ((const float4*)src)[rem];
        const float xs[4] = {s.x, s.y, s.z, s.w};
        bf16x4_t h;
        #pragma unroll
        for (int t = 0; t < 4; ++t) h[t] = (__bf16)xs[t];
        *(bf16x4_t*)(Wall + ((size_t)z << 20) + rem * 4) = h;
        if (z == 0) {
            bf16x4_t l;
            #pragma unroll
            for (int t = 0; t < 4; ++t) l[t] = (__bf16)(xs[t] - (float)h[t]);
            *(bf16x4_t*)(Wqlo + rem * 4) = l;
        }
    } else if (i < 3145728 + 1048576 + 4352) {   // relk hi+lo (272 rows x 64)
        const long ri = i - (3145728 + 1048576);
        const int j  = (int)(ri >> 4);
        const int d4 = (int)(ri & 15) * 4;
        bf16x4_t h, l;
        if (j < 257) {
            const float4 s = *(const float4*)(relk + j * 64 + d4);
            const float xs[4] = {s.x, s.y, s.z, s.w};
            #pragma unroll
            for (int t = 0; t < 4; ++t) {
                h[t] = (__bf16)xs[t];
                l[t] = (__bf16)(xs[t] - (float)h[t]);
            }
        } else {
            #pragma unroll
            for (int t = 0; t < 4; ++t) { h[t] = (__bf16)0.f; l[t] = (__bf16)0.f; }
        }
        *(bf16x4_t*)(relkp + j * 64 + d4) = h;
        *(bf16x4_t*)(relkp + 17408 + j * 64 + d4) = l;
    } else if (i < 3145728 + 1048576 + 4352 + 4608) { // rvT: [64][288], rvT[d][j]=rel_v[j][d]
        const long ri = i - (3145728 + 1048576 + 4352);
        const int d  = (int)(ri / 72);
        const int j4 = (int)(ri % 72) * 4;
        bf16x4_t o;
        #pragma unroll
        for (int t = 0; t < 4; ++t) {
            const int j = j4 + t;
            o[t] = (j < 257) ? (__bf16)relv[j * 64 + d] : (__bf16)0.f;
        }
        *(bf16x4_t*)(rvT + d * 288 + j4) = o;
    }
}

// ---------------------------------------------------------------------------
// Shared 128x128 tile GEMM core: acc += A(128xK) @ W(128xK)^T, K=1024, BK=32.
__device__ __forceinline__ void gemm128_core(
    const __bf16* __restrict__ A, const __bf16* __restrict__ W,
    __bf16* As, __bf16* Ws, f32x4_t acc[4][4])
{
    const int tid  = threadIdx.x;
    const int lane = tid & 63;
    const int quad = lane >> 4;
    const int l15  = lane & 15;
    const int wid  = tid >> 6;
    const int wm = wid >> 1, wn = wid & 1;

    for (int kt = 0; kt < 32; ++kt) {
        #pragma unroll
        for (int r = 0; r < 2; ++r) {
            const int c = r * 256 + tid;        // 512 chunks of 16B per tile
            const int row = c >> 2, kb = c & 3;
            async16(A + row * 1024 + kt * 32 + kb * 8, As + c * 8);
            async16(W + row * 1024 + kt * 32 + kb * 8, Ws + c * 8);
        }
        __syncthreads();
        bf16x8_t af[4], wf[4];
        #pragma unroll
        for (int i = 0; i < 4; ++i) {
            af[i] = *(const bf16x8_t*)(As + (wm * 64 + i * 16 + l15) * 32 + quad * 8);
            wf[i] = *(const bf16x8_t*)(Ws + (wn * 64 + i * 16 + l15) * 32 + quad * 8);
        }
        #pragma unroll
        for (int i = 0; i < 4; ++i)
            #pragma unroll
            for (int j = 0; j < 4; ++j)
                acc[i][j] = MFMA16(af[i], wf[j], acc[i][j]);
        __syncthreads();
    }
}

// ---------------------------------------------------------------------------
// Kernel 2: QKV projections. z=0:Q (W hi+lo), z=1:K [bh][s][d];
// z=2:V pair-tiled [bh][s/32][d][s%32].
__global__ __launch_bounds__(256) void gemm_qkv_kernel(
    const __bf16* __restrict__ Xbf, const __bf16* __restrict__ Wall,
    const __bf16* __restrict__ Wqlo,
    const float* __restrict__ bq, const float* __restrict__ bk, const float* __restrict__ bv,
    __bf16* __restrict__ QKVh)
{
    __shared__ __bf16 As[4096], Ws[4096];
    const int z = blockIdx.z;
    const __bf16* A = Xbf + (size_t)z * 4194304 + (size_t)blockIdx.y * 131072;
    const __bf16* W = Wall + (size_t)z * 1048576 + (size_t)blockIdx.x * 131072;
    f32x4_t acc[4][4];
    #pragma unroll
    for (int i = 0; i < 4; ++i)
        #pragma unroll
        for (int j = 0; j < 4; ++j)
            acc[i][j] = (f32x4_t){0.f, 0.f, 0.f, 0.f};

    gemm128_core(A, W, As, Ws, acc);
    if (z == 0)   // Q = Xhi*(Whi+Wlo)
        gemm128_core(A, Wqlo + (size_t)blockIdx.x * 131072, As, Ws, acc);

    const int tid = threadIdx.x, lane = tid & 63, quad = lane >> 4, l15 = lane & 15;
    const int wid = tid >> 6, wm = wid >> 1, wn = wid & 1;
    const int m0 = blockIdx.y * 128 + wm * 64;
    const int n0 = blockIdx.x * 128 + wn * 64;
    const float* bias = (z == 0) ? bq : ((z == 1) ? bk : bv);
    __bf16* dst = QKVh + (size_t)z * 4194304;

    if (z < 2) {
        #pragma unroll
        for (int j = 0; j < 4; ++j) {
            const int n = n0 + j * 16 + l15;
            const float bn = bias[n];
            #pragma unroll
            for (int i = 0; i < 4; ++i) {
                #pragma unroll
                for (int v = 0; v < 4; ++v) {
                    const int m = m0 + i * 16 + quad * 4 + v;
                    dst[((((m >> 10) * 16 + (n >> 6)) << 16)) + ((m & 1023) << 6) + (n & 63)]
                        = (__bf16)(acc[i][j][v] + bn);
                }
            }
        }
    } else {
        #pragma unroll
        for (int j = 0; j < 4; ++j) {
            const int n = n0 + j * 16 + l15;
            const float bn = bias[n];
            #pragma unroll
            for (int i = 0; i < 4; ++i) {
                const int m = m0 + i * 16 + quad * 4;
                bf16x4_t pk;
                #pragma unroll
                for (int v = 0; v < 4; ++v) pk[v] = (__bf16)(acc[i][j][v] + bn);
                const int s = m & 1023, d = n & 63;
                const size_t idx = (((size_t)((m >> 10) * 16 + (n >> 6))) << 16)
                                 + (size_t)(s >> 5) * 2048 + d * 32 + (s & 31);
                *(bf16x4_t*)(dst + idx) = pk;
            }
        }
    }
}

// ---------------------------------------------------------------------------
// Kernel 5: output projection, fp32 epilogue straight to d_out.
__global__ __launch_bounds__(256) void gemm_out_kernel(
    const __bf16* __restrict__ ctx, const __bf16* __restrict__ Wo,
    const float* __restrict__ bo, float* __restrict__ out)
{
    __shared__ __bf16 As[4096], Ws[4096];
    const __bf16* A = ctx + (size_t)blockIdx.y * 131072;
    const __bf16* W = Wo + (size_t)blockIdx.x * 131072;
    f32x4_t acc[4][4];
    #pragma unroll
    for (int i = 0; i < 4; ++i)
        #pragma unroll
        for (int j = 0; j < 4; ++j)
            acc[i][j] = (f32x4_t){0.f, 0.f, 0.f, 0.f};
    gemm128_core(A, W, As, Ws, acc);

    const int tid = threadIdx.x, lane = tid & 63, quad = lane >> 4, l15 = lane & 15;
    const int wid = tid >> 6, wm = wid >> 1, wn = wid & 1;
    const int m0 = blockIdx.y * 128 + wm * 64;
    const int n0 = blockIdx.x * 128 + wn * 64;
    #pragma unroll
    for (int j = 0; j < 4; ++j) {
        const int n = n0 + j * 16 + l15;
        const float bn = bo[n];
        #pragma unroll
        for (int i = 0; i < 4; ++i)
            #pragma unroll
            for (int v = 0; v < 4; ++v) {
                const int m = m0 + i * 16 + quad * 4 + v;
                out[(size_t)m * 1024 + n] = acc[i][j][v] + bn;
            }
    }
}

// ---------------------------------------------------------------------------
// Kernel 3a: qrel GEMM. qrelG[bh][l][j] = Q[bh,l]·rel_k[j] (hi+lo), fp16 out.
__global__ __launch_bounds__(256) void qrel_kernel(
    const __bf16* __restrict__ Qh, const __bf16* __restrict__ relkp,
    _Float16* __restrict__ qrelG)
{
    const int tid = threadIdx.x, lane = tid & 63, wid = tid >> 6;
    const int quad = lane >> 4, l15 = lane & 15;
    const int bh = blockIdx.y;
    const int l0 = blockIdx.x * 64 + wid * 16;
    const __bf16* Qbase = Qh + (size_t)bh * 65536;
    const __bf16* relk_hi = relkp;
    const __bf16* relk_lo = relkp + 17408;
    const bf16x8_t aq0 = *(const bf16x8_t*)(Qbase + (l0 + l15) * 64 + quad * 8);
    const bf16x8_t aq1 = *(const bf16x8_t*)(Qbase + (l0 + l15) * 64 + 32 + quad * 8);
    _Float16* out = qrelG + ((size_t)bh * 1024 + l0) * 272;
    for (int nt = 0; nt < 17; ++nt) {
        const int j = nt * 16 + l15;
        const bf16x8_t h0  = *(const bf16x8_t*)(relk_hi + j * 64 + quad * 8);
        const bf16x8_t h1  = *(const bf16x8_t*)(relk_hi + j * 64 + 32 + quad * 8);
        const bf16x8_t lo0 = *(const bf16x8_t*)(relk_lo + j * 64 + quad * 8);
        const bf16x8_t lo1 = *(const bf16x8_t*)(relk_lo + j * 64 + 32 + quad * 8);
        f32x4_t c = (f32x4_t){0.f, 0.f, 0.f, 0.f};
        c = MFMA16(aq0, lo0, c);
        c = MFMA16(aq1, lo1, c);
        c = MFMA16(aq0, h0, c);
        c = MFMA16(aq1, h1, c);
        #pragma unroll
        for (int v = 0; v < 4; ++v)
            out[(quad * 4 + v) * 272 + j] = (_Float16)c[v];
    }
}

// ---------------------------------------------------------------------------
// Kernel 3b: FAR attention, cooperative. Block = 256 thr (4 waves) owning a
// 64-row q-chunk; waves own 16 rows each. Loop over 32 k-pairs: K-pair (4KB)
// and V-pair (4KB) staged to LDS via global_load_lds (coalesced; XOR swizzle
// on the global side so LDS frag reads are ~2-way-conflict max). Far slots
// only (band slots zeroed in p_s); rel_v enters rank-1 via e0/e1.
__global__ __launch_bounds__(256, 4) void attn_far_kernel(
    const __bf16* __restrict__ Qh, const __bf16* __restrict__ Kh,
    const __bf16* __restrict__ Vt, const _Float16* __restrict__ qrelG,
    const int* __restrict__ mask, const float* __restrict__ relv,
    float* __restrict__ OfarG, float* __restrict__ rsG)
{
    __shared__ __align__(16) __bf16 Ks[2048];       // 32r x 64d, swizzled
    __shared__ __align__(16) __bf16 Vs[2048];       // 64d x 32r, swizzled
    __shared__ __align__(16) __bf16 p_s[4][16][40];

    const int tid = threadIdx.x, lane = tid & 63, wid = tid >> 6;
    const int quad = lane >> 4, l15 = lane & 15;
    // XCD-affine swizzle: 1024 blocks = 8 xcd x (8 bh x 16 chunks)
    const int lin = blockIdx.x;
    const int slot = lin >> 3;
    const int bh = (lin & 7) + 8 * (slot >> 4);
    const int chunk = slot & 15;
    const int b = bh >> 4;
    const int t0w = chunk * 4 + wid;        // this wave's q-tile index
    const int l0 = t0w * 16;

    const __bf16* Qbase = Qh + (size_t)bh * 65536;
    const __bf16* Kbase = Kh + (size_t)bh * 65536;
    const __bf16* Vbase = Vt + (size_t)bh * 65536;
    const _Float16* qr  = qrelG + ((size_t)bh * 1024 + l0) * 272;
    const int* maskb = mask + b * 1024;

    const bf16x8_t aq0 = *(const bf16x8_t*)(Qbase + (l0 + l15) * 64 + quad * 8);
    const bf16x8_t aq1 = *(const bf16x8_t*)(Qbase + (l0 + l15) * 64 + 32 + quad * 8);

    float c0[4], c1[4];
    #pragma unroll
    for (int v = 0; v < 4; ++v) {
        c0[v] = (float)qr[(quad * 4 + v) * 272 + 0];
        c1[v] = (float)qr[(quad * 4 + v) * 272 + 256];
    }

    // static per-lane staging offsets (2 chunks per lane per pair)
    int gK[2], lK[2], gV[2], lV[2];
    #pragma unroll
    for (int ii = 0; ii < 2; ++ii) {
        const int ch = (wid & 1) * 128 + ii * 64 + lane;   // 0..255
        {   // K: chunk ch -> row r pos p holds global chunk g = p ^ (r&7)
            const int r = ch >> 3, p = ch & 7, g = p ^ (r & 7);
            gK[ii] = r * 64 + g * 8;
            lK[ii] = ch * 8;
        }
        {   // V: chunk ch -> d-row, pos p holds g = p ^ ((d>>1)&3)
            const int d = ch >> 2, p = ch & 3, g = p ^ ((d >> 1) & 3);
            gV[ii] = d * 32 + g * 8;
            lV[ii] = ch * 8;
        }
    }

    f32x4_t o[4];
    #pragma unroll
    for (int dt = 0; dt < 4; ++dt) o[dt] = (f32x4_t){0.f, 0.f, 0.f, 0.f};
    float e0[4] = {0.f, 0.f, 0.f, 0.f};
    float e1[4] = {0.f, 0.f, 0.f, 0.f};

    for (int pc = 0; pc < 32; ++pc) {
        const int rb0 = pc * 32;
        if (wid < 2) {
            #pragma unroll
            for (int ii = 0; ii < 2; ++ii)
                async16(Kbase + rb0 * 64 + gK[ii], Ks + lK[ii]);
        } else {
            #pragma unroll
            for (int ii = 0; ii < 2; ++ii)
                async16(Vbase + pc * 2048 + gV[ii], Vs + lV[ii]);
        }
        __syncthreads();

        const int tI0 = pc * 2;
        const bool far0 = (tI0 <= t0w - 9) || (tI0 >= t0w + 9);
        const bool far1 = (tI0 + 1 <= t0w - 9) || (tI0 + 1 >= t0w + 9);
        if (far0 || far1) {
            #pragma unroll
            for (int sl = 0; sl < 2; ++sl) {
                const bool isFar = sl ? far1 : far0;
                if (isFar) {
                    const int R = sl * 16 + l15;
                    const bf16x8_t kb0 =
                        *(const bf16x8_t*)(Ks + R * 64 + (quad ^ (R & 7)) * 8);
                    const bf16x8_t kb1 =
                        *(const bf16x8_t*)(Ks + R * 64 + (((quad + 4) ^ (R & 7))) * 8);
                    f32x4_t s = (f32x4_t){0.f, 0.f, 0.f, 0.f};
                    s = MFMA16(aq0, kb0, s);
                    s = MFMA16(aq1, kb1, s);
                    const float madd = (maskb[rb0 + R] == 0) ? -1.0e9f : 0.f;
                    const bool isLo = (tI0 + sl < t0w);
                    #pragma unroll
                    for (int v = 0; v < 4; ++v) {
                        const float cc = isLo ? c0[v] : c1[v];
                        const float p = __expf(fmaf(s[v], SCALE, cc) + madd);
                        const __bf16 pb = (__bf16)p;
                        const float pf = (float)pb;
                        if (isLo) e0[v] += pf; else e1[v] += pf;
                        p_s[wid][quad * 4 + v][sl * 16 + l15] = pb;
                    }
                } else {
                    #pragma unroll
                    for (int v = 0; v < 4; ++v)
                        p_s[wid][quad * 4 + v][sl * 16 + l15] = (__bf16)0.f;
                }
            }
            const bf16x8_t pa = *(const bf16x8_t*)(&p_s[wid][l15][quad * 8]);
            #pragma unroll
            for (int dt = 0; dt < 4; ++dt) {
                const int D = dt * 16 + l15;
                const bf16x8_t vb =
                    *(const bf16x8_t*)(Vs + D * 32 + ((quad ^ ((D >> 1) & 3))) * 8);
                o[dt] = MFMA16(pa, vb, o[dt]);
            }
        }
        __syncthreads();
    }

    // reduce e0/e1 across the 16 lanes of each quad
    #pragma unroll
    for (int v = 0; v < 4; ++v)
        #pragma unroll
        for (int mm = 1; mm < 16; mm <<= 1) {
            e0[v] += __shfl_xor(e0[v], mm, 64);
            e1[v] += __shfl_xor(e1[v], mm, 64);
        }

    // epilogue (per wave; no cross-wave merge needed)
    float* Od = OfarG + ((size_t)bh * 1024 + l0) * 64;
    #pragma unroll
    for (int dt = 0; dt < 4; ++dt) {
        const int d = dt * 16 + l15;
        const float rv0   = relv[d];
        const float rv256 = relv[256 * 64 + d];
        #pragma unroll
        for (int v = 0; v < 4; ++v)
            Od[(quad * 4 + v) * 64 + d] = o[dt][v] + e0[v] * rv0 + e1[v] * rv256;
    }
    if (l15 == 0) {
        #pragma unroll
        for (int v = 0; v < 4; ++v)
            rsG[bh * 1024 + l0 + quad * 4 + v] = e0[v] + e1[v];
    }
}

// ---------------------------------------------------------------------------
// Kernel 4: BAND attention. One wave per q-tile, 17 band r-tiles, w_s LDS
// histogram + w @ rel_v, merges O_far, normalizes, writes ctx. Zero barriers.
__global__ __launch_bounds__(64, 4) void attn_band_kernel(
    const __bf16* __restrict__ Qh, const __bf16* __restrict__ Kh,
    const __bf16* __restrict__ Vt, const _Float16* __restrict__ qrelG,
    const __bf16* __restrict__ rvT, const int* __restrict__ mask,
    const float* __restrict__ OfarG, const float* __restrict__ rsG,
    __bf16* __restrict__ ctx)
{
    __shared__ __align__(16) __bf16 w_s[16][288];
    __shared__ __align__(16) __bf16 p_s[16][40];

    const int lane = threadIdx.x & 63;
    const int quad = lane >> 4, l15 = lane & 15;
    const int lin = blockIdx.x;
    const int slot = lin >> 3;
    const int bh = (lin & 7) + 8 * (slot >> 6);
    const int t0 = slot & 63, l0 = t0 * 16;
    const int b = bh >> 4;

    const __bf16* Qbase = Qh + (size_t)bh * 65536;
    const __bf16* Kbase = Kh + (size_t)bh * 65536;
    const __bf16* Vbase = Vt + (size_t)bh * 65536;
    const _Float16* qr  = qrelG + ((size_t)bh * 1024 + l0) * 272;

    {   // zero w_s
        uint4* wz = (uint4*)&w_s[0][0];
        for (int t = lane; t < 576; t += 64) wz[t] = (uint4){0u, 0u, 0u, 0u};
    }

    const bf16x8_t aq0 = *(const bf16x8_t*)(Qbase + (l0 + l15) * 64 + quad * 8);
    const bf16x8_t aq1 = *(const bf16x8_t*)(Qbase + (l0 + l15) * 64 + 32 + quad * 8);

    const int tstart = t0 > 8 ? t0 - 8 : 0;
    const int tend   = t0 < 55 ? t0 + 8 : 63;
    const int nb = tend - tstart + 1;

    f32x4_t o[4];
    #pragma unroll
    for (int dt = 0; dt < 4; ++dt) o[dt] = (f32x4_t){0.f, 0.f, 0.f, 0.f};
    float rowsum[4] = {0.f, 0.f, 0.f, 0.f};
    float e0[4] = {0.f, 0.f, 0.f, 0.f};
    float e1[4] = {0.f, 0.f, 0.f, 0.f};

    for (int m = 0; m < nb; m += 2) {
        const int rbA = (tstart + m) * 16;
        const bool hasB = (m + 1 < nb);
        const int rbB = hasB ? rbA + 16 : rbA;
        #pragma unroll
        for (int slotn = 0; slotn < 2; ++slotn) {
            if (slotn == 1 && !hasB) {
                #pragma unroll
                for (int v = 0; v < 4; ++v)
                    p_s[quad * 4 + v][16 + l15] = (__bf16)0.f;
                break;
            }
            const int rb = slotn ? rbB : rbA;
            const int r = rb + l15;
            const bf16x8_t kb0 = *(const bf16x8_t*)(Kbase + r * 64 + quad * 8);
            const bf16x8_t kb1 = *(const bf16x8_t*)(Kbase + r * 64 + 32 + quad * 8);
            f32x4_t s = (f32x4_t){0.f, 0.f, 0.f, 0.f};
            s = MFMA16(aq0, kb0, s);
            s = MFMA16(aq1, kb1, s);
            const float madd = (mask[b * 1024 + r] == 0) ? -1.0e9f : 0.f;
            #pragma unroll
            for (int v = 0; v < 4; ++v) {
                const int lrow = quad * 4 + v;
                const int dd = r - (l0 + lrow);
                int j = dd + 128; j = j < 0 ? 0 : (j > 256 ? 256 : j);
                const float bias = (float)qr[lrow * 272 + j];
                const float p = __expf(fmaf(s[v], SCALE, bias) + madd);
                const __bf16 pb = (__bf16)p;
                const float pf = (float)pb;
                rowsum[v] += pf;
                p_s[lrow][slotn * 16 + l15] = pb;
                if (j == 0)        e0[v] += pf;
                else if (j == 256) e1[v] += pf;
                else               w_s[lrow][j] = pb;
            }
        }
        const bf16x8_t pa = *(const bf16x8_t*)(&p_s[l15][quad * 8]);
        const int rr = (quad < 2) ? (rbA + quad * 8) : (rbB + (quad - 2) * 8);
        #pragma unroll
        for (int dt = 0; dt < 4; ++dt) {
            const bf16x8_t vb = *(const bf16x8_t*)(
                Vbase + (rr >> 5) * 2048 + (dt * 16 + l15) * 32 + (rr & 31));
            o[dt] = MFMA16(pa, vb, o[dt]);
        }
    }

    #pragma unroll
    for (int v = 0; v < 4; ++v) {
        #pragma unroll
        for (int mm = 1; mm < 16; mm <<= 1) {
            rowsum[v] += __shfl_xor(rowsum[v], mm, 64);
            e0[v]     += __shfl_xor(e0[v], mm, 64);
            e1[v]     += __shfl_xor(e1[v], mm, 64);
        }
    }
    if (l15 == 0) {
        #pragma unroll
        for (int v = 0; v < 4; ++v) {
            w_s[quad * 4 + v][0]   = (__bf16)e0[v];
            w_s[quad * 4 + v][256] = (__bf16)e1[v];
        }
    }

    for (int kc = 0; kc < 9; ++kc) {
        const bf16x8_t wa = *(const bf16x8_t*)(&w_s[l15][kc * 32 + quad * 8]);
        #pragma unroll
        for (int dt = 0; dt < 4; ++dt) {
            const bf16x8_t rb =
                *(const bf16x8_t*)(rvT + (dt * 16 + l15) * 288 + kc * 32 + quad * 8);
            o[dt] = MFMA16(wa, rb, o[dt]);
        }
    }

    float rinv[4];
    #pragma unroll
    for (int v = 0; v < 4; ++v)
        rinv[v] = 1.f / (rowsum[v] + rsG[bh * 1024 + l0 + quad * 4 + v]);
    const float* Od = OfarG + ((size_t)bh * 1024 + l0) * 64;
    const int h = bh & 15;
    #pragma unroll
    for (int dt = 0; dt < 4; ++dt)
        #pragma unroll
        for (int v = 0; v < 4; ++v) {
            const int lrow = quad * 4 + v;
            const float val = (o[dt][v] + Od[lrow * 64 + dt * 16 + l15]) * rinv[v];
            ctx[((size_t)b * 1024 + l0 + lrow) * 1024 + h * 64 + dt * 16 + l15]
                = (__bf16)val;
        }
}

// ---------------------------------------------------------------------------
extern "C" void kernel_launch(void* const* d_in, const int* in_sizes, int n_in,
                              void* d_out, int out_size, void* d_ws, size_t ws_size,
                              hipStream_t stream)
{
    const float* q    = (const float*)d_in[0];
    const float* k    = (const float*)d_in[1];
    const float* v    = (const float*)d_in[2];
    const int*   mask = (const int*)  d_in[3];
    const float* wq   = (const float*)d_in[4];
    const float* bq   = (const float*)d_in[5];
    const float* wk   = (const float*)d_in[6];
    const float* bk   = (const float*)d_in[7];
    const float* wv   = (const float*)d_in[8];
    const float* bv   = (const float*)d_in[9];
    const float* wo   = (const float*)d_in[10];
    const float* bo   = (const float*)d_in[11];
    const float* relk = (const float*)d_in[12];
    const float* relv = (const float*)d_in[13];

    // workspace layout (bf16 elements unless noted); ~94 MB total.
    __bf16* Xbf   = (__bf16*)d_ws;            // 12582912 (q,k,v inputs hi)
    __bf16* Xgap  = Xbf   + 12582912;         // 4194304 (dead; qrelG overlay pad)
    __bf16* Wqlo  = Xgap  + 4194304;          // 1048576 (wq residual)
    __bf16* Wall  = Wqlo  + 1048576;          // 4194304 (wq,wk,wv,wo hi)
    __bf16* QKVh  = Wall  + 4194304;          // 12582912 (Q, K, V pair-tiled)
    __bf16* ctx   = QKVh  + 12582912;         // 4194304
    __bf16* relkp = ctx   + 4194304;          // 34816 (hi | lo)
    __bf16* rvT   = relkp + 34816;            // 18432
    float*  OfarG = (float*)(rvT + 18432);    // 4194304 floats
    float*  rsG   = OfarG + 4194304;          // 65536 floats
    _Float16* qrelG = (_Float16*)d_ws;        // overlay, written after qkv

    cast_all_kernel<<<16419, 256, 0, stream>>>(q, k, v, wq, wk, wv, wo, relk, relv,
                                               Xbf, Wall, relkp, rvT, Wqlo);
    gemm_qkv_kernel<<<dim3(8, 32, 3), 256, 0, stream>>>(Xbf, Wall, Wqlo,
                                                        bq, bk, bv, QKVh);
    qrel_kernel<<<dim3(16, 64), 256, 0, stream>>>(QKVh, relkp, qrelG);
    attn_far_kernel<<<1024, 256, 0, stream>>>(QKVh, QKVh + 4194304,
                                              QKVh + 2 * 4194304, qrelG, mask,
                                              relv, OfarG, rsG);
    attn_band_kernel<<<4096, 64, 0, stream>>>(QKVh, QKVh + 4194304,
                                              QKVh + 2 * 4194304, qrelG,
                                              rvT, mask, OfarG, rsG, ctx);
    gemm_out_kernel<<<dim3(8, 32, 1), 256, 0, stream>>>(ctx, Wall + 3 * 1048576,
                                                        bo, (float*)d_out);
}